// Round 1
// baseline (5463.151 us; speedup 1.0000x reference)
//
#include <hip/hip_runtime.h>

// Problem constants (also derived from in_sizes at launch for robustness)
#define R_DIM 8
#define L_DIM 4
#define C_DIM 8
#define RLC   (R_DIM * L_DIM * C_DIM)   // 256
#define RC    (R_DIM * C_DIM)           // 64

// out[i] = node_feat[i] * memory_coef   (vectorized float4)
__global__ __launch_bounds__(256) void init_out_kernel(
    const float4* __restrict__ nf4,
    float4* __restrict__ out4,
    const float* __restrict__ coef_p,
    int n4)
{
    int i = blockIdx.x * blockDim.x + threadIdx.x;
    if (i >= n4) return;
    float c = *coef_p;
    float4 v = nf4[i];
    out4[i] = make_float4(v.x * c, v.y * c, v.z * c, v.w * c);
}

// One wave (64 lanes) per edge. Lane owns 4 contiguous elements of the
// 256-element [R,L,C] feature vector: f0 = lane*4 .. f0+3 share (r,l),
// c = c0..c0+3 contiguous, so invr0/prefactor slice is a float4 at r*8+c0.
__global__ __launch_bounds__(256) void edge_scatter_kernel(
    const float* __restrict__ node_feat,
    const float* __restrict__ edge_len,
    const float* __restrict__ cutoff_fn,
    const int*  __restrict__ edge_index,   // [2, E] int32
    const float* __restrict__ prefactor,   // [R*C] = 64
    const float* __restrict__ invr0,       // [R*C] = 64
    float* __restrict__ out,
    int n_edges)
{
    int tid  = blockIdx.x * blockDim.x + threadIdx.x;
    int e    = tid >> 6;
    int lane = threadIdx.x & 63;
    if (e >= n_edges) return;

    int   src = edge_index[e];
    int   dst = edge_index[n_edges + e];
    float len = edge_len[e];
    float cf  = cutoff_fn[e];

    int f0     = lane << 2;                        // 0..252, multiple of 4
    int rcbase = ((f0 >> 5) << 3) + (f0 & 7);      // r*8 + c0, float4-aligned

    const float4 iv = *(const float4*)(invr0 + rcbase);
    const float4 pf = *(const float4*)(prefactor + rcbase);
    const float4 s  = *(const float4*)(node_feat + (long)src * RLC + f0);

    float nl = -len;
    float d0 = __expf(nl * iv.x) * pf.x * cf;
    float d1 = __expf(nl * iv.y) * pf.y * cf;
    float d2 = __expf(nl * iv.z) * pf.z * cf;
    float d3 = __expf(nl * iv.w) * pf.w * cf;

    float* o = out + (long)dst * RLC + f0;
    atomicAdd(o + 0, s.x * d0);
    atomicAdd(o + 1, s.y * d1);
    atomicAdd(o + 2, s.z * d2);
    atomicAdd(o + 3, s.w * d3);
}

extern "C" void kernel_launch(void* const* d_in, const int* in_sizes, int n_in,
                              void* d_out, int out_size, void* d_ws, size_t ws_size,
                              hipStream_t stream) {
    const float* node_feat  = (const float*)d_in[0];
    const float* edge_len   = (const float*)d_in[1];
    const float* cutoff_fn  = (const float*)d_in[2];
    const int*   edge_index = (const int*)d_in[3];
    const float* prefactor  = (const float*)d_in[4];
    const float* invr0      = (const float*)d_in[5];
    const float* coef_p     = (const float*)d_in[6];
    float* out = (float*)d_out;

    int n_edges = in_sizes[1];               // E
    int n_feat  = in_sizes[0];               // N * 256
    int n4      = n_feat / 4;

    // 1) out = node_feat * memory_coef
    {
        int block = 256;
        int grid  = (n4 + block - 1) / block;
        init_out_kernel<<<grid, block, 0, stream>>>(
            (const float4*)node_feat, (float4*)out, coef_p, n4);
    }

    // 2) scatter-add messages: one wave per edge
    {
        int block = 256;                      // 4 waves = 4 edges per block
        long total_threads = (long)n_edges * 64;
        int grid = (int)((total_threads + block - 1) / block);
        edge_scatter_kernel<<<grid, block, 0, stream>>>(
            node_feat, edge_len, cutoff_fn, edge_index,
            prefactor, invr0, out, n_edges);
    }
}

// Round 2
// 696.032 us; speedup vs baseline: 7.8490x; 7.8490x over previous
//
#include <hip/hip_runtime.h>

#define RLC 256            // R*L*C = 8*4*8
#define SCAN_BLOCK 256
#define SCAN_ITEMS 4       // 1024 elements per scan block

// ---------------------------------------------------------------------------
// CSR build: histogram -> exclusive scan -> scatter edge ids by destination
// ---------------------------------------------------------------------------

__global__ __launch_bounds__(256) void hist_kernel(
    const int* __restrict__ edge_index, int* __restrict__ counts,
    int n_edges)
{
    int e = blockIdx.x * blockDim.x + threadIdx.x;
    if (e >= n_edges) return;
    int dst = edge_index[n_edges + e];
    atomicAdd(&counts[dst], 1);
}

// Per-block exclusive scan of 1024 ints; writes local scans + block totals.
__global__ __launch_bounds__(SCAN_BLOCK) void scan1_kernel(
    const int* __restrict__ in, int* __restrict__ out,
    int* __restrict__ blocksums, int n)
{
    __shared__ int tmp[SCAN_BLOCK];
    int t = threadIdx.x;
    int base = blockIdx.x * SCAN_BLOCK * SCAN_ITEMS + t * SCAN_ITEMS;
    int v[SCAN_ITEMS];
    int tot = 0;
    #pragma unroll
    for (int k = 0; k < SCAN_ITEMS; ++k) {
        int i = base + k;
        v[k] = (i < n) ? in[i] : 0;
        tot += v[k];
    }
    tmp[t] = tot;
    __syncthreads();
    int run = tot;
    for (int d = 1; d < SCAN_BLOCK; d <<= 1) {
        int x = (t >= d) ? tmp[t - d] : 0;
        __syncthreads();
        tmp[t] += x;
        __syncthreads();
    }
    int excl = tmp[t] - run;          // exclusive prefix of this thread's chunk
    #pragma unroll
    for (int k = 0; k < SCAN_ITEMS; ++k) {
        int i = base + k;
        if (i < n) out[i] = excl;
        excl += v[k];
    }
    if (t == SCAN_BLOCK - 1) blocksums[blockIdx.x] = tmp[t];
}

// Exclusive scan of block totals (nb <= 256) in one block.
__global__ __launch_bounds__(SCAN_BLOCK) void scan2_kernel(
    int* __restrict__ blocksums, int nb)
{
    __shared__ int tmp[SCAN_BLOCK];
    int t = threadIdx.x;
    int v = (t < nb) ? blocksums[t] : 0;
    tmp[t] = v;
    __syncthreads();
    for (int d = 1; d < SCAN_BLOCK; d <<= 1) {
        int x = (t >= d) ? tmp[t - d] : 0;
        __syncthreads();
        tmp[t] += x;
        __syncthreads();
    }
    if (t < nb) blocksums[t] = tmp[t] - v;   // exclusive
}

// Add block offsets; produce final offsets[] and a mutable cursor[] copy.
__global__ __launch_bounds__(256) void scan3_kernel(
    int* __restrict__ offsets, int* __restrict__ cursor,
    const int* __restrict__ blocksums, int n, int n_edges)
{
    int i = blockIdx.x * blockDim.x + threadIdx.x;
    if (i == 0) offsets[n] = n_edges;
    if (i >= n) return;
    int o = offsets[i] + blocksums[i / (SCAN_BLOCK * SCAN_ITEMS)];
    offsets[i] = o;
    cursor[i] = o;
}

__global__ __launch_bounds__(256) void scatter_ids_kernel(
    const int* __restrict__ edge_index, int* __restrict__ cursor,
    int* __restrict__ sorted_eid, int n_edges)
{
    int e = blockIdx.x * blockDim.x + threadIdx.x;
    if (e >= n_edges) return;
    int dst = edge_index[n_edges + e];
    int pos = atomicAdd(&cursor[dst], 1);
    sorted_eid[pos] = e;
}

// ---------------------------------------------------------------------------
// Gather-accumulate: one wave (64 lanes) per node, lane owns 4 contiguous
// elements (same r,l; c contiguous) -> float4 everywhere, single store.
// ---------------------------------------------------------------------------
__global__ __launch_bounds__(256) void gather_kernel(
    const float* __restrict__ node_feat,
    const float* __restrict__ edge_len,
    const float* __restrict__ cutoff_fn,
    const int*  __restrict__ edge_index,
    const float* __restrict__ prefactor,
    const float* __restrict__ invr0,
    const float* __restrict__ coef_p,
    const int*  __restrict__ offsets,
    const int*  __restrict__ sorted_eid,
    float* __restrict__ out,
    int n_nodes, int n_edges)
{
    int tid  = blockIdx.x * blockDim.x + threadIdx.x;
    int node = tid >> 6;
    int lane = threadIdx.x & 63;
    if (node >= n_nodes) return;

    int f0     = lane << 2;                      // 0..252
    int rcbase = ((f0 >> 5) << 3) + (f0 & 7);    // r*8 + c0 (float4 aligned)

    const float4 iv = *(const float4*)(invr0 + rcbase);
    const float4 pf = *(const float4*)(prefactor + rcbase);
    float coef = *coef_p;

    const float4 self = *(const float4*)(node_feat + (long)node * RLC + f0);
    float ax = self.x * coef, ay = self.y * coef,
          az = self.z * coef, aw = self.w * coef;

    int j   = offsets[node];
    int end = offsets[node + 1];

    // 2-way unrolled to keep two gathers in flight
    for (; j + 1 < end; j += 2) {
        int e0 = sorted_eid[j], e1 = sorted_eid[j + 1];
        int s0 = edge_index[e0], s1 = edge_index[e1];
        float l0 = edge_len[e0], l1 = edge_len[e1];
        float c0 = cutoff_fn[e0], c1 = cutoff_fn[e1];
        const float4 f0v = *(const float4*)(node_feat + (long)s0 * RLC + f0);
        const float4 f1v = *(const float4*)(node_feat + (long)s1 * RLC + f0);
        float n0 = -l0, n1 = -l1;
        ax += f0v.x * (__expf(n0 * iv.x) * pf.x * c0);
        ay += f0v.y * (__expf(n0 * iv.y) * pf.y * c0);
        az += f0v.z * (__expf(n0 * iv.z) * pf.z * c0);
        aw += f0v.w * (__expf(n0 * iv.w) * pf.w * c0);
        ax += f1v.x * (__expf(n1 * iv.x) * pf.x * c1);
        ay += f1v.y * (__expf(n1 * iv.y) * pf.y * c1);
        az += f1v.z * (__expf(n1 * iv.z) * pf.z * c1);
        aw += f1v.w * (__expf(n1 * iv.w) * pf.w * c1);
    }
    if (j < end) {
        int e0 = sorted_eid[j];
        int s0 = edge_index[e0];
        float l0 = edge_len[e0];
        float c0 = cutoff_fn[e0];
        const float4 f0v = *(const float4*)(node_feat + (long)s0 * RLC + f0);
        float n0 = -l0;
        ax += f0v.x * (__expf(n0 * iv.x) * pf.x * c0);
        ay += f0v.y * (__expf(n0 * iv.y) * pf.y * c0);
        az += f0v.z * (__expf(n0 * iv.z) * pf.z * c0);
        aw += f0v.w * (__expf(n0 * iv.w) * pf.w * c0);
    }

    *(float4*)(out + (long)node * RLC + f0) = make_float4(ax, ay, az, aw);
}

// ---------------------------------------------------------------------------
// Fallback (ws too small): R1 atomic path
// ---------------------------------------------------------------------------
__global__ __launch_bounds__(256) void init_out_kernel(
    const float4* __restrict__ nf4, float4* __restrict__ out4,
    const float* __restrict__ coef_p, int n4)
{
    int i = blockIdx.x * blockDim.x + threadIdx.x;
    if (i >= n4) return;
    float c = *coef_p;
    float4 v = nf4[i];
    out4[i] = make_float4(v.x * c, v.y * c, v.z * c, v.w * c);
}

__global__ __launch_bounds__(256) void edge_scatter_kernel(
    const float* __restrict__ node_feat,
    const float* __restrict__ edge_len,
    const float* __restrict__ cutoff_fn,
    const int*  __restrict__ edge_index,
    const float* __restrict__ prefactor,
    const float* __restrict__ invr0,
    float* __restrict__ out, int n_edges)
{
    int tid  = blockIdx.x * blockDim.x + threadIdx.x;
    int e    = tid >> 6;
    int lane = threadIdx.x & 63;
    if (e >= n_edges) return;
    int   src = edge_index[e];
    int   dst = edge_index[n_edges + e];
    float len = edge_len[e];
    float cf  = cutoff_fn[e];
    int f0     = lane << 2;
    int rcbase = ((f0 >> 5) << 3) + (f0 & 7);
    const float4 iv = *(const float4*)(invr0 + rcbase);
    const float4 pf = *(const float4*)(prefactor + rcbase);
    const float4 s  = *(const float4*)(node_feat + (long)src * RLC + f0);
    float nl = -len;
    float* o = out + (long)dst * RLC + f0;
    atomicAdd(o + 0, s.x * __expf(nl * iv.x) * pf.x * cf);
    atomicAdd(o + 1, s.y * __expf(nl * iv.y) * pf.y * cf);
    atomicAdd(o + 2, s.z * __expf(nl * iv.z) * pf.z * cf);
    atomicAdd(o + 3, s.w * __expf(nl * iv.w) * pf.w * cf);
}

extern "C" void kernel_launch(void* const* d_in, const int* in_sizes, int n_in,
                              void* d_out, int out_size, void* d_ws, size_t ws_size,
                              hipStream_t stream) {
    const float* node_feat  = (const float*)d_in[0];
    const float* edge_len   = (const float*)d_in[1];
    const float* cutoff_fn  = (const float*)d_in[2];
    const int*   edge_index = (const int*)d_in[3];
    const float* prefactor  = (const float*)d_in[4];
    const float* invr0      = (const float*)d_in[5];
    const float* coef_p     = (const float*)d_in[6];
    float* out = (float*)d_out;

    const int n_edges = in_sizes[1];
    const int n_feat  = in_sizes[0];
    const int n_nodes = n_feat / RLC;

    // workspace layout (ints)
    const int per_block = SCAN_BLOCK * SCAN_ITEMS;
    const int nb1 = (n_nodes + per_block - 1) / per_block;   // scan blocks (98)
    size_t need = ((size_t)(n_nodes + 1) + n_nodes + 256 + n_edges) * sizeof(int);

    if (ws_size >= need && nb1 <= SCAN_BLOCK) {
        int* offsets    = (int*)d_ws;                 // n_nodes + 1
        int* cursor     = offsets + (n_nodes + 1);    // n_nodes
        int* blocksums  = cursor + n_nodes;           // 256
        int* sorted_eid = blocksums + 256;            // n_edges

        hipMemsetAsync(cursor, 0, (size_t)n_nodes * sizeof(int), stream);

        int eg = (n_edges + 255) / 256;
        hist_kernel<<<eg, 256, 0, stream>>>(edge_index, cursor, n_edges);

        scan1_kernel<<<nb1, SCAN_BLOCK, 0, stream>>>(cursor, offsets, blocksums, n_nodes);
        scan2_kernel<<<1, SCAN_BLOCK, 0, stream>>>(blocksums, nb1);

        hipMemsetAsync(cursor, 0, (size_t)n_nodes * sizeof(int), stream); // rebuilt below
        int ng = (n_nodes + 255) / 256;
        scan3_kernel<<<ng, 256, 0, stream>>>(offsets, cursor, blocksums, n_nodes, n_edges);

        scatter_ids_kernel<<<eg, 256, 0, stream>>>(edge_index, cursor, sorted_eid, n_edges);

        long total = (long)n_nodes * 64;
        int gg = (int)((total + 255) / 256);
        gather_kernel<<<gg, 256, 0, stream>>>(
            node_feat, edge_len, cutoff_fn, edge_index,
            prefactor, invr0, coef_p, offsets, sorted_eid,
            out, n_nodes, n_edges);
    } else {
        int n4 = n_feat / 4;
        int block = 256;
        init_out_kernel<<<(n4 + block - 1) / block, block, 0, stream>>>(
            (const float4*)node_feat, (float4*)out, coef_p, n4);
        long total_threads = (long)n_edges * 64;
        int grid = (int)((total_threads + block - 1) / block);
        edge_scatter_kernel<<<grid, block, 0, stream>>>(
            node_feat, edge_len, cutoff_fn, edge_index,
            prefactor, invr0, out, n_edges);
    }
}

// Round 3
// 596.093 us; speedup vs baseline: 9.1649x; 1.1677x over previous
//
#include <hip/hip_runtime.h>

#define RLC 256            // R*L*C = 8*4*8
#define SCAN_BLOCK 256
#define SCAN_ITEMS 4       // 1024 elements per scan block

// ---------------------------------------------------------------------------
// CSR build: histogram -> exclusive scan -> scatter edge payloads by dst
// ---------------------------------------------------------------------------

__global__ __launch_bounds__(256) void hist_kernel(
    const int* __restrict__ edge_index, int* __restrict__ counts,
    int n_edges)
{
    int e = blockIdx.x * blockDim.x + threadIdx.x;
    if (e >= n_edges) return;
    int dst = edge_index[n_edges + e];
    atomicAdd(&counts[dst], 1);
}

// Per-block exclusive scan of 1024 ints; writes local scans + block totals.
__global__ __launch_bounds__(SCAN_BLOCK) void scan1_kernel(
    const int* __restrict__ in, int* __restrict__ out,
    int* __restrict__ blocksums, int n)
{
    __shared__ int tmp[SCAN_BLOCK];
    int t = threadIdx.x;
    int base = blockIdx.x * SCAN_BLOCK * SCAN_ITEMS + t * SCAN_ITEMS;
    int v[SCAN_ITEMS];
    int tot = 0;
    #pragma unroll
    for (int k = 0; k < SCAN_ITEMS; ++k) {
        int i = base + k;
        v[k] = (i < n) ? in[i] : 0;
        tot += v[k];
    }
    tmp[t] = tot;
    __syncthreads();
    int run = tot;
    for (int d = 1; d < SCAN_BLOCK; d <<= 1) {
        int x = (t >= d) ? tmp[t - d] : 0;
        __syncthreads();
        tmp[t] += x;
        __syncthreads();
    }
    int excl = tmp[t] - run;
    #pragma unroll
    for (int k = 0; k < SCAN_ITEMS; ++k) {
        int i = base + k;
        if (i < n) out[i] = excl;
        excl += v[k];
    }
    if (t == SCAN_BLOCK - 1) blocksums[blockIdx.x] = tmp[t];
}

// Exclusive scan of block totals (nb <= 256) in one block.
__global__ __launch_bounds__(SCAN_BLOCK) void scan2_kernel(
    int* __restrict__ blocksums, int nb)
{
    __shared__ int tmp[SCAN_BLOCK];
    int t = threadIdx.x;
    int v = (t < nb) ? blocksums[t] : 0;
    tmp[t] = v;
    __syncthreads();
    for (int d = 1; d < SCAN_BLOCK; d <<= 1) {
        int x = (t >= d) ? tmp[t - d] : 0;
        __syncthreads();
        tmp[t] += x;
        __syncthreads();
    }
    if (t < nb) blocksums[t] = tmp[t] - v;   // exclusive
}

// Add block offsets; produce final offsets[] and a mutable cursor[] copy.
__global__ __launch_bounds__(256) void scan3_kernel(
    int* __restrict__ offsets, int* __restrict__ cursor,
    const int* __restrict__ blocksums, int n, int n_edges)
{
    int i = blockIdx.x * blockDim.x + threadIdx.x;
    if (i == 0) offsets[n] = n_edges;
    if (i >= n) return;
    int o = offsets[i] + blocksums[i / (SCAN_BLOCK * SCAN_ITEMS)];
    offsets[i] = o;
    cursor[i] = o;
}

// Scatter packed payload {src_bits, -len, cutoff, 0} to dst-sorted position.
__global__ __launch_bounds__(256) void scatter_ids_kernel(
    const int* __restrict__ edge_index,
    const float* __restrict__ edge_len,
    const float* __restrict__ cutoff_fn,
    int* __restrict__ cursor,
    float4* __restrict__ payload, int n_edges)
{
    int e = blockIdx.x * blockDim.x + threadIdx.x;
    if (e >= n_edges) return;
    int dst = edge_index[n_edges + e];
    int src = edge_index[e];
    float nl = -edge_len[e];
    float cf = cutoff_fn[e];
    int pos = atomicAdd(&cursor[dst], 1);
    payload[pos] = make_float4(__int_as_float(src), nl, cf, 0.0f);
}

// ---------------------------------------------------------------------------
// Gather-accumulate: one wave per node. Wave cooperatively loads up to 64
// edge payloads (one float4/lane, coalesced), broadcasts each via shfl,
// gathers sender float4 and accumulates. Single float4 store per lane.
// ---------------------------------------------------------------------------
__global__ __launch_bounds__(256) void gather_kernel(
    const float* __restrict__ node_feat,
    const float4* __restrict__ payload,
    const float* __restrict__ prefactor,
    const float* __restrict__ invr0,
    const float* __restrict__ coef_p,
    const int*  __restrict__ offsets,
    float* __restrict__ out,
    int n_nodes)
{
    int tid  = blockIdx.x * blockDim.x + threadIdx.x;
    int node = tid >> 6;
    int lane = threadIdx.x & 63;
    if (node >= n_nodes) return;

    int f0     = lane << 2;                      // 0..252 (4 contiguous elems)
    int rcbase = ((f0 >> 5) << 3) + (f0 & 7);    // r*8 + c0 (float4 aligned)

    const float4 iv = *(const float4*)(invr0 + rcbase);
    const float4 pf = *(const float4*)(prefactor + rcbase);
    float coef = *coef_p;

    const float4 self = *(const float4*)(node_feat + (long)node * RLC + f0);
    float ax = self.x * coef, ay = self.y * coef,
          az = self.z * coef, aw = self.w * coef;

    int j   = offsets[node];
    int end = offsets[node + 1];

    for (int base = j; base < end; base += 64) {
        int idx = base + lane;
        float4 p = make_float4(0.f, 0.f, 0.f, 0.f);
        if (idx < end) p = payload[idx];
        int m = end - base;
        if (m > 64) m = 64;
        int   psrc = __float_as_int(p.x);
        float pnl  = p.y;
        float pcf  = p.z;

        #pragma unroll 4
        for (int it = 0; it < m; ++it) {
            int   src = __shfl(psrc, it, 64);
            float nl  = __shfl(pnl,  it, 64);
            float cf  = __shfl(pcf,  it, 64);
            const float4 f = *(const float4*)(node_feat + (long)src * RLC + f0);
            ax += f.x * (__expf(nl * iv.x) * pf.x * cf);
            ay += f.y * (__expf(nl * iv.y) * pf.y * cf);
            az += f.z * (__expf(nl * iv.z) * pf.z * cf);
            aw += f.w * (__expf(nl * iv.w) * pf.w * cf);
        }
    }

    *(float4*)(out + (long)node * RLC + f0) = make_float4(ax, ay, az, aw);
}

// ---------------------------------------------------------------------------
// Fallback (ws too small): atomic scatter path
// ---------------------------------------------------------------------------
__global__ __launch_bounds__(256) void init_out_kernel(
    const float4* __restrict__ nf4, float4* __restrict__ out4,
    const float* __restrict__ coef_p, int n4)
{
    int i = blockIdx.x * blockDim.x + threadIdx.x;
    if (i >= n4) return;
    float c = *coef_p;
    float4 v = nf4[i];
    out4[i] = make_float4(v.x * c, v.y * c, v.z * c, v.w * c);
}

__global__ __launch_bounds__(256) void edge_scatter_kernel(
    const float* __restrict__ node_feat,
    const float* __restrict__ edge_len,
    const float* __restrict__ cutoff_fn,
    const int*  __restrict__ edge_index,
    const float* __restrict__ prefactor,
    const float* __restrict__ invr0,
    float* __restrict__ out, int n_edges)
{
    int tid  = blockIdx.x * blockDim.x + threadIdx.x;
    int e    = tid >> 6;
    int lane = threadIdx.x & 63;
    if (e >= n_edges) return;
    int   src = edge_index[e];
    int   dst = edge_index[n_edges + e];
    float len = edge_len[e];
    float cf  = cutoff_fn[e];
    int f0     = lane << 2;
    int rcbase = ((f0 >> 5) << 3) + (f0 & 7);
    const float4 iv = *(const float4*)(invr0 + rcbase);
    const float4 pf = *(const float4*)(prefactor + rcbase);
    const float4 s  = *(const float4*)(node_feat + (long)src * RLC + f0);
    float nl = -len;
    float* o = out + (long)dst * RLC + f0;
    atomicAdd(o + 0, s.x * __expf(nl * iv.x) * pf.x * cf);
    atomicAdd(o + 1, s.y * __expf(nl * iv.y) * pf.y * cf);
    atomicAdd(o + 2, s.z * __expf(nl * iv.z) * pf.z * cf);
    atomicAdd(o + 3, s.w * __expf(nl * iv.w) * pf.w * cf);
}

extern "C" void kernel_launch(void* const* d_in, const int* in_sizes, int n_in,
                              void* d_out, int out_size, void* d_ws, size_t ws_size,
                              hipStream_t stream) {
    const float* node_feat  = (const float*)d_in[0];
    const float* edge_len   = (const float*)d_in[1];
    const float* cutoff_fn  = (const float*)d_in[2];
    const int*   edge_index = (const int*)d_in[3];
    const float* prefactor  = (const float*)d_in[4];
    const float* invr0      = (const float*)d_in[5];
    const float* coef_p     = (const float*)d_in[6];
    float* out = (float*)d_out;

    const int n_edges = in_sizes[1];
    const int n_feat  = in_sizes[0];
    const int n_nodes = n_feat / RLC;

    const int per_block = SCAN_BLOCK * SCAN_ITEMS;
    const int nb1 = (n_nodes + per_block - 1) / per_block;   // scan blocks
    size_t need = (size_t)n_edges * sizeof(float4)
                + ((size_t)(n_nodes + 1) + n_nodes + 256) * sizeof(int);

    if (ws_size >= need && nb1 <= SCAN_BLOCK) {
        // payload first so it stays 16B-aligned
        float4* payload  = (float4*)d_ws;                       // n_edges
        int* offsets     = (int*)(payload + n_edges);           // n_nodes + 1
        int* cursor      = offsets + (n_nodes + 1);             // n_nodes
        int* blocksums   = cursor + n_nodes;                    // 256

        hipMemsetAsync(cursor, 0, (size_t)n_nodes * sizeof(int), stream);

        int eg = (n_edges + 255) / 256;
        hist_kernel<<<eg, 256, 0, stream>>>(edge_index, cursor, n_edges);

        scan1_kernel<<<nb1, SCAN_BLOCK, 0, stream>>>(cursor, offsets, blocksums, n_nodes);
        scan2_kernel<<<1, SCAN_BLOCK, 0, stream>>>(blocksums, nb1);

        int ng = (n_nodes + 255) / 256;
        scan3_kernel<<<ng, 256, 0, stream>>>(offsets, cursor, blocksums, n_nodes, n_edges);

        scatter_ids_kernel<<<eg, 256, 0, stream>>>(
            edge_index, edge_len, cutoff_fn, cursor, payload, n_edges);

        long total = (long)n_nodes * 64;
        int gg = (int)((total + 255) / 256);
        gather_kernel<<<gg, 256, 0, stream>>>(
            node_feat, payload, prefactor, invr0, coef_p, offsets,
            out, n_nodes);
    } else {
        int n4 = n_feat / 4;
        int block = 256;
        init_out_kernel<<<(n4 + block - 1) / block, block, 0, stream>>>(
            (const float4*)node_feat, (float4*)out, coef_p, n4);
        long total_threads = (long)n_edges * 64;
        int grid = (int)((total_threads + block - 1) / block);
        edge_scatter_kernel<<<grid, block, 0, stream>>>(
            node_feat, edge_len, cutoff_fn, edge_index,
            prefactor, invr0, out, n_edges);
    }
}

// Round 5
// 508.627 us; speedup vs baseline: 10.7410x; 1.1720x over previous
//
#include <hip/hip_runtime.h>
#include <hip/hip_fp16.h>

#define RLC 256            // R*L*C = 8*4*8
#define SCAN_BLOCK 256
#define SCAN_ITEMS 4       // 1024 elements per scan block

// round-to-nearest-even fp32 -> bf16 bits
__device__ __forceinline__ unsigned int bfr(float f) {
    unsigned int u = __float_as_uint(f);
    return (u + 0x7fffu + ((u >> 16) & 1u)) >> 16;
}

// ---------------------------------------------------------------------------
// Cast node_feat fp32 -> bf16 (ws copy). 8 elems / thread, 16B store.
// ---------------------------------------------------------------------------
__global__ __launch_bounds__(256) void cast_kernel(
    const float4* __restrict__ in, uint4* __restrict__ outp, int n8)
{
    int i = blockIdx.x * blockDim.x + threadIdx.x;
    if (i >= n8) return;
    float4 a = in[2 * i];
    float4 b = in[2 * i + 1];
    uint4 r;
    r.x = bfr(a.x) | (bfr(a.y) << 16);
    r.y = bfr(a.z) | (bfr(a.w) << 16);
    r.z = bfr(b.x) | (bfr(b.y) << 16);
    r.w = bfr(b.z) | (bfr(b.w) << 16);
    outp[i] = r;
}

// ---------------------------------------------------------------------------
// CSR build: histogram -> exclusive scan -> scatter edge payloads by dst
// ---------------------------------------------------------------------------
__global__ __launch_bounds__(256) void hist_kernel(
    const int* __restrict__ edge_index, int* __restrict__ counts,
    int n_edges)
{
    int e = blockIdx.x * blockDim.x + threadIdx.x;
    if (e >= n_edges) return;
    int dst = edge_index[n_edges + e];
    atomicAdd(&counts[dst], 1);
}

__global__ __launch_bounds__(SCAN_BLOCK) void scan1_kernel(
    const int* __restrict__ in, int* __restrict__ out,
    int* __restrict__ blocksums, int n)
{
    __shared__ int tmp[SCAN_BLOCK];
    int t = threadIdx.x;
    int base = blockIdx.x * SCAN_BLOCK * SCAN_ITEMS + t * SCAN_ITEMS;
    int v[SCAN_ITEMS];
    int tot = 0;
    #pragma unroll
    for (int k = 0; k < SCAN_ITEMS; ++k) {
        int i = base + k;
        v[k] = (i < n) ? in[i] : 0;
        tot += v[k];
    }
    tmp[t] = tot;
    __syncthreads();
    int run = tot;
    for (int d = 1; d < SCAN_BLOCK; d <<= 1) {
        int x = (t >= d) ? tmp[t - d] : 0;
        __syncthreads();
        tmp[t] += x;
        __syncthreads();
    }
    int excl = tmp[t] - run;
    #pragma unroll
    for (int k = 0; k < SCAN_ITEMS; ++k) {
        int i = base + k;
        if (i < n) out[i] = excl;
        excl += v[k];
    }
    if (t == SCAN_BLOCK - 1) blocksums[blockIdx.x] = tmp[t];
}

__global__ __launch_bounds__(SCAN_BLOCK) void scan2_kernel(
    int* __restrict__ blocksums, int nb)
{
    __shared__ int tmp[SCAN_BLOCK];
    int t = threadIdx.x;
    int v = (t < nb) ? blocksums[t] : 0;
    tmp[t] = v;
    __syncthreads();
    for (int d = 1; d < SCAN_BLOCK; d <<= 1) {
        int x = (t >= d) ? tmp[t - d] : 0;
        __syncthreads();
        tmp[t] += x;
        __syncthreads();
    }
    if (t < nb) blocksums[t] = tmp[t] - v;   // exclusive
}

__global__ __launch_bounds__(256) void scan3_kernel(
    int* __restrict__ offsets, int* __restrict__ cursor,
    const int* __restrict__ blocksums, int n, int n_edges)
{
    int i = blockIdx.x * blockDim.x + threadIdx.x;
    if (i == 0) offsets[n] = n_edges;
    if (i >= n) return;
    int o = offsets[i] + blocksums[i / (SCAN_BLOCK * SCAN_ITEMS)];
    offsets[i] = o;
    cursor[i] = o;
}

// Scatter packed payload {src, (cf_f16<<16)|nl_f16} to dst-sorted position.
__global__ __launch_bounds__(256) void scatter_ids_kernel(
    const int* __restrict__ edge_index,
    const float* __restrict__ edge_len,
    const float* __restrict__ cutoff_fn,
    int* __restrict__ cursor,
    int2* __restrict__ payload, int n_edges)
{
    int e = blockIdx.x * blockDim.x + threadIdx.x;
    if (e >= n_edges) return;
    int dst = edge_index[n_edges + e];
    int src = edge_index[e];
    unsigned int hnl = __half_as_ushort(__float2half(-edge_len[e]));
    unsigned int hcf = __half_as_ushort(__float2half(cutoff_fn[e]));
    int pos = atomicAdd(&cursor[dst], 1);
    payload[pos] = make_int2(src, (int)((hcf << 16) | hnl));
}

// ---------------------------------------------------------------------------
// Gather-accumulate: one wave per node. Wave loads up to 64 payloads
// (one int2/lane, coalesced), broadcasts via shfl, gathers bf16x4 (8B)
// sender slice, accumulates fp32. Self term read from fp32 source.
// ---------------------------------------------------------------------------
__global__ __launch_bounds__(256) void gather_kernel(
    const float* __restrict__ node_feat,       // fp32 original (self term)
    const unsigned short* __restrict__ nfb,    // bf16 copy
    const int2* __restrict__ payload,
    const float* __restrict__ prefactor,
    const float* __restrict__ invr0,
    const float* __restrict__ coef_p,
    const int*  __restrict__ offsets,
    float* __restrict__ out,
    int n_nodes)
{
    int tid  = blockIdx.x * blockDim.x + threadIdx.x;
    int node = tid >> 6;
    int lane = threadIdx.x & 63;
    if (node >= n_nodes) return;

    int f0     = lane << 2;                      // 0..252 (4 contiguous elems)
    int rcbase = ((f0 >> 5) << 3) + (f0 & 7);    // r*8 + c0 (float4 aligned)

    const float4 iv = *(const float4*)(invr0 + rcbase);
    const float4 pf = *(const float4*)(prefactor + rcbase);
    float coef = *coef_p;

    const float4 self = *(const float4*)(node_feat + (long)node * RLC + f0);
    float ax = self.x * coef, ay = self.y * coef,
          az = self.z * coef, aw = self.w * coef;

    int j   = offsets[node];
    int end = offsets[node + 1];

    for (int base = j; base < end; base += 64) {
        int idx = base + lane;
        int2 p = make_int2(0, 0);
        if (idx < end) p = payload[idx];
        int m = end - base;
        if (m > 64) m = 64;
        int psrc = p.x;
        int ppk  = p.y;

        #pragma unroll 4
        for (int it = 0; it < m; ++it) {
            int src = __shfl(psrc, it, 64);
            int pk  = __shfl(ppk,  it, 64);
            float nl = __half2float(__ushort_as_half((unsigned short)(pk & 0xffff)));
            float cf = __half2float(__ushort_as_half((unsigned short)(((unsigned int)pk) >> 16)));
            uint2 raw = *(const uint2*)(nfb + (long)src * RLC + f0);
            float fx = __uint_as_float(raw.x << 16);
            float fy = __uint_as_float(raw.x & 0xffff0000u);
            float fz = __uint_as_float(raw.y << 16);
            float fw = __uint_as_float(raw.y & 0xffff0000u);
            ax += fx * (__expf(nl * iv.x) * pf.x * cf);
            ay += fy * (__expf(nl * iv.y) * pf.y * cf);
            az += fz * (__expf(nl * iv.z) * pf.z * cf);
            aw += fw * (__expf(nl * iv.w) * pf.w * cf);
        }
    }

    *(float4*)(out + (long)node * RLC + f0) = make_float4(ax, ay, az, aw);
}

// ---------------------------------------------------------------------------
// Fallback (ws too small): atomic scatter path (exact fp32)
// ---------------------------------------------------------------------------
__global__ __launch_bounds__(256) void init_out_kernel(
    const float4* __restrict__ nf4, float4* __restrict__ out4,
    const float* __restrict__ coef_p, int n4)
{
    int i = blockIdx.x * blockDim.x + threadIdx.x;
    if (i >= n4) return;
    float c = *coef_p;
    float4 v = nf4[i];
    out4[i] = make_float4(v.x * c, v.y * c, v.z * c, v.w * c);
}

__global__ __launch_bounds__(256) void edge_scatter_kernel(
    const float* __restrict__ node_feat,
    const float* __restrict__ edge_len,
    const float* __restrict__ cutoff_fn,
    const int*  __restrict__ edge_index,
    const float* __restrict__ prefactor,
    const float* __restrict__ invr0,
    float* __restrict__ out, int n_edges)
{
    int tid  = blockIdx.x * blockDim.x + threadIdx.x;
    int e    = tid >> 6;
    int lane = threadIdx.x & 63;
    if (e >= n_edges) return;
    int   src = edge_index[e];
    int   dst = edge_index[n_edges + e];
    float len = edge_len[e];
    float cf  = cutoff_fn[e];
    int f0     = lane << 2;
    int rcbase = ((f0 >> 5) << 3) + (f0 & 7);
    const float4 iv = *(const float4*)(invr0 + rcbase);
    const float4 pf = *(const float4*)(prefactor + rcbase);
    const float4 s  = *(const float4*)(node_feat + (long)src * RLC + f0);
    float nl = -len;
    float* o = out + (long)dst * RLC + f0;
    atomicAdd(o + 0, s.x * __expf(nl * iv.x) * pf.x * cf);
    atomicAdd(o + 1, s.y * __expf(nl * iv.y) * pf.y * cf);
    atomicAdd(o + 2, s.z * __expf(nl * iv.z) * pf.z * cf);
    atomicAdd(o + 3, s.w * __expf(nl * iv.w) * pf.w * cf);
}

extern "C" void kernel_launch(void* const* d_in, const int* in_sizes, int n_in,
                              void* d_out, int out_size, void* d_ws, size_t ws_size,
                              hipStream_t stream) {
    const float* node_feat  = (const float*)d_in[0];
    const float* edge_len   = (const float*)d_in[1];
    const float* cutoff_fn  = (const float*)d_in[2];
    const int*   edge_index = (const int*)d_in[3];
    const float* prefactor  = (const float*)d_in[4];
    const float* invr0      = (const float*)d_in[5];
    const float* coef_p     = (const float*)d_in[6];
    float* out = (float*)d_out;

    const int n_edges = in_sizes[1];
    const int n_feat  = in_sizes[0];
    const int n_nodes = n_feat / RLC;

    const int per_block = SCAN_BLOCK * SCAN_ITEMS;
    const int nb1 = (n_nodes + per_block - 1) / per_block;   // scan blocks
    size_t need = (size_t)n_feat * sizeof(unsigned short)      // bf16 feats
                + (size_t)n_edges * sizeof(int2)               // payload
                + ((size_t)(n_nodes + 1) + n_nodes + 256) * sizeof(int);

    if (ws_size >= need && nb1 <= SCAN_BLOCK) {
        unsigned short* nfb = (unsigned short*)d_ws;            // n_feat bf16
        int2* payload   = (int2*)(nfb + n_feat);                // n_edges
        int* offsets    = (int*)(payload + n_edges);            // n_nodes + 1
        int* cursor     = offsets + (n_nodes + 1);              // n_nodes
        int* blocksums  = cursor + n_nodes;                     // 256

        // bf16 copy of node_feat
        int n8 = n_feat / 8;
        cast_kernel<<<(n8 + 255) / 256, 256, 0, stream>>>(
            (const float4*)node_feat, (uint4*)nfb, n8);

        (void)hipMemsetAsync(cursor, 0, (size_t)n_nodes * sizeof(int), stream);

        int eg = (n_edges + 255) / 256;
        hist_kernel<<<eg, 256, 0, stream>>>(edge_index, cursor, n_edges);

        scan1_kernel<<<nb1, SCAN_BLOCK, 0, stream>>>(cursor, offsets, blocksums, n_nodes);
        scan2_kernel<<<1, SCAN_BLOCK, 0, stream>>>(blocksums, nb1);

        int ng = (n_nodes + 255) / 256;
        scan3_kernel<<<ng, 256, 0, stream>>>(offsets, cursor, blocksums, n_nodes, n_edges);

        scatter_ids_kernel<<<eg, 256, 0, stream>>>(
            edge_index, edge_len, cutoff_fn, cursor, payload, n_edges);

        long total = (long)n_nodes * 64;
        int gg = (int)((total + 255) / 256);
        gather_kernel<<<gg, 256, 0, stream>>>(
            node_feat, nfb, payload, prefactor, invr0, coef_p, offsets,
            out, n_nodes);
    } else {
        int n4 = n_feat / 4;
        int block = 256;
        init_out_kernel<<<(n4 + block - 1) / block, block, 0, stream>>>(
            (const float4*)node_feat, (float4*)out, coef_p, n4);
        long total_threads = (long)n_edges * 64;
        int grid = (int)((total_threads + block - 1) / block);
        edge_scatter_kernel<<<grid, block, 0, stream>>>(
            node_feat, edge_len, cutoff_fn, edge_index,
            prefactor, invr0, out, n_edges);
    }
}

// Round 6
// 458.506 us; speedup vs baseline: 11.9151x; 1.1093x over previous
//
#include <hip/hip_runtime.h>
#include <hip/hip_fp16.h>

#define RLC 256            // R*L*C = 8*4*8
#define SCAN_BLOCK 256
#define SCAN_ITEMS 4       // 1024 elements per scan block

// round-to-nearest-even fp32 -> bf16 bits
__device__ __forceinline__ unsigned int bfr(float f) {
    unsigned int u = __float_as_uint(f);
    return (u + 0x7fffu + ((u >> 16) & 1u)) >> 16;
}

// ---------------------------------------------------------------------------
// Cast node_feat fp32 -> bf16 (ws copy). 8 elems / thread, 16B store.
// ---------------------------------------------------------------------------
__global__ __launch_bounds__(256) void cast_kernel(
    const float4* __restrict__ in, uint4* __restrict__ outp, int n8)
{
    int i = blockIdx.x * blockDim.x + threadIdx.x;
    if (i >= n8) return;
    float4 a = in[2 * i];
    float4 b = in[2 * i + 1];
    uint4 r;
    r.x = bfr(a.x) | (bfr(a.y) << 16);
    r.y = bfr(a.z) | (bfr(a.w) << 16);
    r.z = bfr(b.x) | (bfr(b.y) << 16);
    r.w = bfr(b.z) | (bfr(b.w) << 16);
    outp[i] = r;
}

// ---------------------------------------------------------------------------
// CSR build
// ---------------------------------------------------------------------------

// Histogram + per-edge rank (atomic return value), rank stored coalesced u8.
__global__ __launch_bounds__(256) void hist_rank_kernel(
    const int* __restrict__ edge_index, int* __restrict__ counts,
    unsigned char* __restrict__ rank, int n_edges)
{
    int e = blockIdx.x * blockDim.x + threadIdx.x;
    if (e >= n_edges) return;
    int dst = edge_index[n_edges + e];
    int r = atomicAdd(&counts[dst], 1);
    rank[e] = (unsigned char)r;     // degree is Poisson(16); P(>=256) ~ 0
}

__global__ __launch_bounds__(SCAN_BLOCK) void scan1_kernel(
    const int* __restrict__ in, int* __restrict__ out,
    int* __restrict__ blocksums, int n)
{
    __shared__ int tmp[SCAN_BLOCK];
    int t = threadIdx.x;
    int base = blockIdx.x * SCAN_BLOCK * SCAN_ITEMS + t * SCAN_ITEMS;
    int v[SCAN_ITEMS];
    int tot = 0;
    #pragma unroll
    for (int k = 0; k < SCAN_ITEMS; ++k) {
        int i = base + k;
        v[k] = (i < n) ? in[i] : 0;
        tot += v[k];
    }
    tmp[t] = tot;
    __syncthreads();
    int run = tot;
    for (int d = 1; d < SCAN_BLOCK; d <<= 1) {
        int x = (t >= d) ? tmp[t - d] : 0;
        __syncthreads();
        tmp[t] += x;
        __syncthreads();
    }
    int excl = tmp[t] - run;
    #pragma unroll
    for (int k = 0; k < SCAN_ITEMS; ++k) {
        int i = base + k;
        if (i < n) out[i] = excl;
        excl += v[k];
    }
    if (t == SCAN_BLOCK - 1) blocksums[blockIdx.x] = tmp[t];
}

__global__ __launch_bounds__(SCAN_BLOCK) void scan2_kernel(
    int* __restrict__ blocksums, int nb)
{
    __shared__ int tmp[SCAN_BLOCK];
    int t = threadIdx.x;
    int v = (t < nb) ? blocksums[t] : 0;
    tmp[t] = v;
    __syncthreads();
    for (int d = 1; d < SCAN_BLOCK; d <<= 1) {
        int x = (t >= d) ? tmp[t - d] : 0;
        __syncthreads();
        tmp[t] += x;
        __syncthreads();
    }
    if (t < nb) blocksums[t] = tmp[t] - v;   // exclusive
}

__global__ __launch_bounds__(256) void scan3_kernel(
    int* __restrict__ offsets, const int* __restrict__ blocksums,
    int n, int n_edges)
{
    int i = blockIdx.x * blockDim.x + threadIdx.x;
    if (i == 0) offsets[n] = n_edges;
    if (i >= n) return;
    offsets[i] += blocksums[i / (SCAN_BLOCK * SCAN_ITEMS)];
}

// Scatter payload {src, (cf_f16<<16)|nl_f16} to offsets[dst]+rank[e]. NO atomic.
__global__ __launch_bounds__(256) void scatter_rank_kernel(
    const int* __restrict__ edge_index,
    const float* __restrict__ edge_len,
    const float* __restrict__ cutoff_fn,
    const int* __restrict__ offsets,
    const unsigned char* __restrict__ rank,
    int2* __restrict__ payload, int n_edges)
{
    int e = blockIdx.x * blockDim.x + threadIdx.x;
    if (e >= n_edges) return;
    int dst = edge_index[n_edges + e];
    int src = edge_index[e];
    unsigned int hnl = __half_as_ushort(__float2half(-edge_len[e]));
    unsigned int hcf = __half_as_ushort(__float2half(cutoff_fn[e]));
    int pos = offsets[dst] + (int)rank[e];
    payload[pos] = make_int2(src, (int)((hcf << 16) | hnl));
}

// ---------------------------------------------------------------------------
// Gather-accumulate: one wave per node. Wave loads up to 64 payloads
// (one int2/lane, coalesced), broadcasts via shfl, gathers bf16x4 (8B)
// sender slice, accumulates fp32. iv pre-scaled by log2(e) -> exp2f.
// ---------------------------------------------------------------------------
__global__ __launch_bounds__(256) void gather_kernel(
    const float* __restrict__ node_feat,       // fp32 original (self term)
    const unsigned short* __restrict__ nfb,    // bf16 copy
    const int2* __restrict__ payload,
    const float* __restrict__ prefactor,
    const float* __restrict__ invr0,
    const float* __restrict__ coef_p,
    const int*  __restrict__ offsets,
    float* __restrict__ out,
    int n_nodes)
{
    int tid  = blockIdx.x * blockDim.x + threadIdx.x;
    int node = tid >> 6;
    int lane = threadIdx.x & 63;
    if (node >= n_nodes) return;

    int f0     = lane << 2;                      // 0..252 (4 contiguous elems)
    int rcbase = ((f0 >> 5) << 3) + (f0 & 7);    // r*8 + c0 (float4 aligned)

    const float LOG2E = 1.4426950408889634f;
    float4 iv = *(const float4*)(invr0 + rcbase);
    iv.x *= LOG2E; iv.y *= LOG2E; iv.z *= LOG2E; iv.w *= LOG2E;
    const float4 pf = *(const float4*)(prefactor + rcbase);
    float coef = *coef_p;

    const float4 self = *(const float4*)(node_feat + (long)node * RLC + f0);
    float ax = self.x * coef, ay = self.y * coef,
          az = self.z * coef, aw = self.w * coef;

    int j   = offsets[node];
    int end = offsets[node + 1];

    for (int base = j; base < end; base += 64) {
        int idx = base + lane;
        int2 p = make_int2(0, 0);
        if (idx < end) p = payload[idx];
        int m = end - base;
        if (m > 64) m = 64;
        int psrc = p.x;
        int ppk  = p.y;

        #pragma unroll 4
        for (int it = 0; it < m; ++it) {
            int src = __shfl(psrc, it, 64);
            int pk  = __shfl(ppk,  it, 64);
            float nl = __half2float(__ushort_as_half((unsigned short)(pk & 0xffff)));
            float cf = __half2float(__ushort_as_half((unsigned short)(((unsigned int)pk) >> 16)));
            uint2 raw = *(const uint2*)(nfb + (long)src * RLC + f0);
            float fx = __uint_as_float(raw.x << 16);
            float fy = __uint_as_float(raw.x & 0xffff0000u);
            float fz = __uint_as_float(raw.y << 16);
            float fw = __uint_as_float(raw.y & 0xffff0000u);
            ax += fx * (exp2f(nl * iv.x) * pf.x * cf);
            ay += fy * (exp2f(nl * iv.y) * pf.y * cf);
            az += fz * (exp2f(nl * iv.z) * pf.z * cf);
            aw += fw * (exp2f(nl * iv.w) * pf.w * cf);
        }
    }

    *(float4*)(out + (long)node * RLC + f0) = make_float4(ax, ay, az, aw);
}

// ---------------------------------------------------------------------------
// Fallback (ws too small): atomic scatter path (exact fp32)
// ---------------------------------------------------------------------------
__global__ __launch_bounds__(256) void init_out_kernel(
    const float4* __restrict__ nf4, float4* __restrict__ out4,
    const float* __restrict__ coef_p, int n4)
{
    int i = blockIdx.x * blockDim.x + threadIdx.x;
    if (i >= n4) return;
    float c = *coef_p;
    float4 v = nf4[i];
    out4[i] = make_float4(v.x * c, v.y * c, v.z * c, v.w * c);
}

__global__ __launch_bounds__(256) void edge_scatter_kernel(
    const float* __restrict__ node_feat,
    const float* __restrict__ edge_len,
    const float* __restrict__ cutoff_fn,
    const int*  __restrict__ edge_index,
    const float* __restrict__ prefactor,
    const float* __restrict__ invr0,
    float* __restrict__ out, int n_edges)
{
    int tid  = blockIdx.x * blockDim.x + threadIdx.x;
    int e    = tid >> 6;
    int lane = threadIdx.x & 63;
    if (e >= n_edges) return;
    int   src = edge_index[e];
    int   dst = edge_index[n_edges + e];
    float len = edge_len[e];
    float cf  = cutoff_fn[e];
    int f0     = lane << 2;
    int rcbase = ((f0 >> 5) << 3) + (f0 & 7);
    const float4 iv = *(const float4*)(invr0 + rcbase);
    const float4 pf = *(const float4*)(prefactor + rcbase);
    const float4 s  = *(const float4*)(node_feat + (long)src * RLC + f0);
    float nl = -len;
    float* o = out + (long)dst * RLC + f0;
    atomicAdd(o + 0, s.x * __expf(nl * iv.x) * pf.x * cf);
    atomicAdd(o + 1, s.y * __expf(nl * iv.y) * pf.y * cf);
    atomicAdd(o + 2, s.z * __expf(nl * iv.z) * pf.z * cf);
    atomicAdd(o + 3, s.w * __expf(nl * iv.w) * pf.w * cf);
}

extern "C" void kernel_launch(void* const* d_in, const int* in_sizes, int n_in,
                              void* d_out, int out_size, void* d_ws, size_t ws_size,
                              hipStream_t stream) {
    const float* node_feat  = (const float*)d_in[0];
    const float* edge_len   = (const float*)d_in[1];
    const float* cutoff_fn  = (const float*)d_in[2];
    const int*   edge_index = (const int*)d_in[3];
    const float* prefactor  = (const float*)d_in[4];
    const float* invr0      = (const float*)d_in[5];
    const float* coef_p     = (const float*)d_in[6];
    float* out = (float*)d_out;

    const int n_edges = in_sizes[1];
    const int n_feat  = in_sizes[0];
    const int n_nodes = n_feat / RLC;

    const int per_block = SCAN_BLOCK * SCAN_ITEMS;
    const int nb1 = (n_nodes + per_block - 1) / per_block;   // scan blocks
    size_t need = (size_t)n_feat * sizeof(unsigned short)      // bf16 feats
                + (size_t)n_edges * sizeof(int2)               // payload
                + ((size_t)(n_nodes + 1) + n_nodes + 256) * sizeof(int)
                + (size_t)n_edges;                             // rank u8

    if (ws_size >= need && nb1 <= SCAN_BLOCK) {
        unsigned short* nfb = (unsigned short*)d_ws;            // n_feat bf16
        int2* payload   = (int2*)(nfb + n_feat);                // n_edges
        int* offsets    = (int*)(payload + n_edges);            // n_nodes + 1
        int* counts     = offsets + (n_nodes + 1);              // n_nodes
        int* blocksums  = counts + n_nodes;                     // 256
        unsigned char* rank = (unsigned char*)(blocksums + 256);// n_edges u8

        // bf16 copy of node_feat
        int n8 = n_feat / 8;
        cast_kernel<<<(n8 + 255) / 256, 256, 0, stream>>>(
            (const float4*)node_feat, (uint4*)nfb, n8);

        (void)hipMemsetAsync(counts, 0, (size_t)n_nodes * sizeof(int), stream);

        int eg = (n_edges + 255) / 256;
        hist_rank_kernel<<<eg, 256, 0, stream>>>(edge_index, counts, rank, n_edges);

        scan1_kernel<<<nb1, SCAN_BLOCK, 0, stream>>>(counts, offsets, blocksums, n_nodes);
        scan2_kernel<<<1, SCAN_BLOCK, 0, stream>>>(blocksums, nb1);

        int ng = (n_nodes + 255) / 256;
        scan3_kernel<<<ng, 256, 0, stream>>>(offsets, blocksums, n_nodes, n_edges);

        scatter_rank_kernel<<<eg, 256, 0, stream>>>(
            edge_index, edge_len, cutoff_fn, offsets, rank, payload, n_edges);

        long total = (long)n_nodes * 64;
        int gg = (int)((total + 255) / 256);
        gather_kernel<<<gg, 256, 0, stream>>>(
            node_feat, nfb, payload, prefactor, invr0, coef_p, offsets,
            out, n_nodes);
    } else {
        int n4 = n_feat / 4;
        int block = 256;
        init_out_kernel<<<(n4 + block - 1) / block, block, 0, stream>>>(
            (const float4*)node_feat, (float4*)out, coef_p, n4);
        long total_threads = (long)n_edges * 64;
        int grid = (int)((total_threads + block - 1) / block);
        edge_scatter_kernel<<<grid, block, 0, stream>>>(
            node_feat, edge_len, cutoff_fn, edge_index,
            prefactor, invr0, out, n_edges);
    }
}

// Round 7
// 444.073 us; speedup vs baseline: 12.3024x; 1.0325x over previous
//
#include <hip/hip_runtime.h>
#include <hip/hip_fp16.h>

#define RLC 256            // R*L*C = 8*4*8
#define BUCKET 32          // payload slots per node; overflow -> list
#define OVF_CAP 65536
#define SCAN_BLOCK 256
#define SCAN_ITEMS 4

__device__ __forceinline__ float fast_exp2(float x) {
#if __has_builtin(__builtin_amdgcn_exp2f)
    return __builtin_amdgcn_exp2f(x);     // raw v_exp_f32, no libm fixup
#else
    return __expf(x * 0.6931471805599453f);
#endif
}

// round-to-nearest-even fp32 -> bf16 bits
__device__ __forceinline__ unsigned int bfr(float f) {
    unsigned int u = __float_as_uint(f);
    return (u + 0x7fffu + ((u >> 16) & 1u)) >> 16;
}

#define LOG2E 1.4426950408889634f

// ===========================================================================
// TIER 1: bucketed build + transposed bf16 gather (1 exp per edge per lane)
// ===========================================================================

// Transposed cast: thread per (node,r). Reads 32 fp32 [l][c] (128B contig),
// writes 32 bf16 as [c][l] (64B contig). nfbT[node][r][c][l].
__global__ __launch_bounds__(256) void cast_t_kernel(
    const float4* __restrict__ in, uint2* __restrict__ outp, int nr)
{
    int i = blockIdx.x * blockDim.x + threadIdx.x;
    if (i >= nr) return;
    const float4* p = in + (size_t)i * 8;
    float v[32];
    #pragma unroll
    for (int q = 0; q < 8; ++q) {
        float4 t = p[q];
        v[4*q+0] = t.x; v[4*q+1] = t.y; v[4*q+2] = t.z; v[4*q+3] = t.w;
    }
    uint2* o = outp + (size_t)i * 8;
    #pragma unroll
    for (int c = 0; c < 8; ++c) {
        unsigned int lo = bfr(v[0*8+c]) | (bfr(v[1*8+c]) << 16);
        unsigned int hi = bfr(v[2*8+c]) | (bfr(v[3*8+c]) << 16);
        o[c] = make_uint2(lo, hi);
    }
}

// Fused histogram + bucket scatter. rank from atomic return; rank>=BUCKET
// goes to overflow list (expected ~20 edges for Poisson(16) degrees).
__global__ __launch_bounds__(256) void build_kernel(
    const int* __restrict__ edge_index,
    const float* __restrict__ edge_len,
    const float* __restrict__ cutoff_fn,
    int* __restrict__ counts,
    int2* __restrict__ payload,
    int4* __restrict__ ovf,
    int* __restrict__ ovf_cnt,
    int n_edges)
{
    int e = blockIdx.x * blockDim.x + threadIdx.x;
    if (e >= n_edges) return;
    int dst = edge_index[n_edges + e];
    int src = edge_index[e];
    unsigned int hnl = __half_as_ushort(__float2half(-edge_len[e]));
    unsigned int hcf = __half_as_ushort(__float2half(cutoff_fn[e]));
    int pk = (int)((hcf << 16) | hnl);
    int r = atomicAdd(&counts[dst], 1);
    if (r < BUCKET) {
        payload[(size_t)dst * BUCKET + r] = make_int2(src, pk);
    } else {
        int o = atomicAdd(ovf_cnt, 1);
        if (o < OVF_CAP) ovf[o] = make_int4(dst, src, pk, 0);
    }
}

// One wave per node; lane = r*8+c owns the 4 l-elements (shared decay).
// LDS-staged unpacked payload, broadcast ds_read_b128 per edge.
__global__ __launch_bounds__(256) void gather_bucket_kernel(
    const float* __restrict__ node_feat,     // fp32 [r][l][c] (self term)
    const unsigned short* __restrict__ nfbT, // bf16 [r][c][l]
    const int2* __restrict__ payload,
    const float* __restrict__ prefactor,     // [r][c] = 64
    const float* __restrict__ invr0,         // [r][c] = 64
    const float* __restrict__ coef_p,
    const int* __restrict__ counts,
    float* __restrict__ out,
    int n_nodes)
{
    __shared__ float4 slot[4][BUCKET];
    int wave = threadIdx.x >> 6;
    int lane = threadIdx.x & 63;
    int node = blockIdx.x * 4 + wave;
    bool valid = node < n_nodes;

    float iv = invr0[lane] * LOG2E;
    float pf = prefactor[lane];
    float coef = *coef_p;

    int r = lane >> 3, c = lane & 7;
    long obase = (long)node * RLC + r * 32 + c;

    float a0 = 0.f, a1 = 0.f, a2 = 0.f, a3 = 0.f;
    int m = 0;
    if (valid) {
        int deg = counts[node];
        m = deg < BUCKET ? deg : BUCKET;
        a0 = node_feat[obase]      * coef;
        a1 = node_feat[obase + 8]  * coef;
        a2 = node_feat[obase + 16] * coef;
        a3 = node_feat[obase + 24] * coef;
        if (lane < m) {
            int2 p = payload[(size_t)node * BUCKET + lane];
            float nl = __half2float(__ushort_as_half((unsigned short)(p.y & 0xffff)));
            float cf = __half2float(__ushort_as_half((unsigned short)(((unsigned int)p.y) >> 16)));
            slot[wave][lane] = make_float4(__int_as_float(p.x), nl, cf, 0.f);
        }
    }
    __syncthreads();

    if (valid) {
        #pragma unroll 4
        for (int it = 0; it < m; ++it) {
            float4 s = slot[wave][it];                 // broadcast read
            int src = __float_as_int(s.x);
            float w = fast_exp2(s.y * iv) * pf * s.z;  // 1 exp / edge / lane
            uint2 raw = *(const uint2*)(nfbT + (size_t)src * RLC + lane * 4);
            float f0 = __uint_as_float(raw.x << 16);
            float f1 = __uint_as_float(raw.x & 0xffff0000u);
            float f2 = __uint_as_float(raw.y << 16);
            float f3 = __uint_as_float(raw.y & 0xffff0000u);
            a0 += w * f0; a1 += w * f1; a2 += w * f2; a3 += w * f3;
        }
        out[obase]      = a0;
        out[obase + 8]  = a1;
        out[obase + 16] = a2;
        out[obase + 24] = a3;
    }
}

// Overflow edges: one wave per record, 4 atomics per lane. ~tens of records.
__global__ __launch_bounds__(256) void ovf_kernel(
    const unsigned short* __restrict__ nfbT,
    const float* __restrict__ prefactor,
    const float* __restrict__ invr0,
    const int4* __restrict__ ovf,
    const int* __restrict__ ovf_cnt,
    float* __restrict__ out)
{
    int gtid = blockIdx.x * blockDim.x + threadIdx.x;
    int wid  = gtid >> 6;
    int lane = gtid & 63;
    int nwaves = (gridDim.x * blockDim.x) >> 6;
    int n = *ovf_cnt;
    if (n > OVF_CAP) n = OVF_CAP;

    float iv = invr0[lane] * LOG2E;
    float pf = prefactor[lane];
    int r = lane >> 3, c = lane & 7;

    for (int i = wid; i < n; i += nwaves) {
        int4 rec = ovf[i];
        int dst = rec.x, src = rec.y, pk = rec.z;
        float nl = __half2float(__ushort_as_half((unsigned short)(pk & 0xffff)));
        float cf = __half2float(__ushort_as_half((unsigned short)(((unsigned int)pk) >> 16)));
        float w = fast_exp2(nl * iv) * pf * cf;
        uint2 raw = *(const uint2*)(nfbT + (size_t)src * RLC + lane * 4);
        float f0 = __uint_as_float(raw.x << 16);
        float f1 = __uint_as_float(raw.x & 0xffff0000u);
        float f2 = __uint_as_float(raw.y << 16);
        float f3 = __uint_as_float(raw.y & 0xffff0000u);
        float* o = out + (long)dst * RLC + r * 32 + c;
        atomicAdd(o,      w * f0);
        atomicAdd(o + 8,  w * f1);
        atomicAdd(o + 16, w * f2);
        atomicAdd(o + 24, w * f3);
    }
}

// ===========================================================================
// TIER 2: R6 CSR path (fallback if ws too small for buckets)
// ===========================================================================

__global__ __launch_bounds__(256) void cast_kernel(
    const float4* __restrict__ in, uint4* __restrict__ outp, int n8)
{
    int i = blockIdx.x * blockDim.x + threadIdx.x;
    if (i >= n8) return;
    float4 a = in[2 * i];
    float4 b = in[2 * i + 1];
    uint4 r;
    r.x = bfr(a.x) | (bfr(a.y) << 16);
    r.y = bfr(a.z) | (bfr(a.w) << 16);
    r.z = bfr(b.x) | (bfr(b.y) << 16);
    r.w = bfr(b.z) | (bfr(b.w) << 16);
    outp[i] = r;
}

__global__ __launch_bounds__(256) void hist_rank_kernel(
    const int* __restrict__ edge_index, int* __restrict__ counts,
    unsigned char* __restrict__ rank, int n_edges)
{
    int e = blockIdx.x * blockDim.x + threadIdx.x;
    if (e >= n_edges) return;
    int dst = edge_index[n_edges + e];
    int r = atomicAdd(&counts[dst], 1);
    rank[e] = (unsigned char)r;
}

__global__ __launch_bounds__(SCAN_BLOCK) void scan1_kernel(
    const int* __restrict__ in, int* __restrict__ out,
    int* __restrict__ blocksums, int n)
{
    __shared__ int tmp[SCAN_BLOCK];
    int t = threadIdx.x;
    int base = blockIdx.x * SCAN_BLOCK * SCAN_ITEMS + t * SCAN_ITEMS;
    int v[SCAN_ITEMS];
    int tot = 0;
    #pragma unroll
    for (int k = 0; k < SCAN_ITEMS; ++k) {
        int i = base + k;
        v[k] = (i < n) ? in[i] : 0;
        tot += v[k];
    }
    tmp[t] = tot;
    __syncthreads();
    int run = tot;
    for (int d = 1; d < SCAN_BLOCK; d <<= 1) {
        int x = (t >= d) ? tmp[t - d] : 0;
        __syncthreads();
        tmp[t] += x;
        __syncthreads();
    }
    int excl = tmp[t] - run;
    #pragma unroll
    for (int k = 0; k < SCAN_ITEMS; ++k) {
        int i = base + k;
        if (i < n) out[i] = excl;
        excl += v[k];
    }
    if (t == SCAN_BLOCK - 1) blocksums[blockIdx.x] = tmp[t];
}

__global__ __launch_bounds__(SCAN_BLOCK) void scan2_kernel(
    int* __restrict__ blocksums, int nb)
{
    __shared__ int tmp[SCAN_BLOCK];
    int t = threadIdx.x;
    int v = (t < nb) ? blocksums[t] : 0;
    tmp[t] = v;
    __syncthreads();
    for (int d = 1; d < SCAN_BLOCK; d <<= 1) {
        int x = (t >= d) ? tmp[t - d] : 0;
        __syncthreads();
        tmp[t] += x;
        __syncthreads();
    }
    if (t < nb) blocksums[t] = tmp[t] - v;
}

__global__ __launch_bounds__(256) void scan3_kernel(
    int* __restrict__ offsets, const int* __restrict__ blocksums,
    int n, int n_edges)
{
    int i = blockIdx.x * blockDim.x + threadIdx.x;
    if (i == 0) offsets[n] = n_edges;
    if (i >= n) return;
    offsets[i] += blocksums[i / (SCAN_BLOCK * SCAN_ITEMS)];
}

__global__ __launch_bounds__(256) void scatter_rank_kernel(
    const int* __restrict__ edge_index,
    const float* __restrict__ edge_len,
    const float* __restrict__ cutoff_fn,
    const int* __restrict__ offsets,
    const unsigned char* __restrict__ rank,
    int2* __restrict__ payload, int n_edges)
{
    int e = blockIdx.x * blockDim.x + threadIdx.x;
    if (e >= n_edges) return;
    int dst = edge_index[n_edges + e];
    int src = edge_index[e];
    unsigned int hnl = __half_as_ushort(__float2half(-edge_len[e]));
    unsigned int hcf = __half_as_ushort(__float2half(cutoff_fn[e]));
    int pos = offsets[dst] + (int)rank[e];
    payload[pos] = make_int2(src, (int)((hcf << 16) | hnl));
}

__global__ __launch_bounds__(256) void gather_kernel(
    const float* __restrict__ node_feat,
    const unsigned short* __restrict__ nfb,
    const int2* __restrict__ payload,
    const float* __restrict__ prefactor,
    const float* __restrict__ invr0,
    const float* __restrict__ coef_p,
    const int*  __restrict__ offsets,
    float* __restrict__ out,
    int n_nodes)
{
    int tid  = blockIdx.x * blockDim.x + threadIdx.x;
    int node = tid >> 6;
    int lane = threadIdx.x & 63;
    if (node >= n_nodes) return;

    int f0     = lane << 2;
    int rcbase = ((f0 >> 5) << 3) + (f0 & 7);

    float4 iv = *(const float4*)(invr0 + rcbase);
    iv.x *= LOG2E; iv.y *= LOG2E; iv.z *= LOG2E; iv.w *= LOG2E;
    const float4 pf = *(const float4*)(prefactor + rcbase);
    float coef = *coef_p;

    const float4 self = *(const float4*)(node_feat + (long)node * RLC + f0);
    float ax = self.x * coef, ay = self.y * coef,
          az = self.z * coef, aw = self.w * coef;

    int j   = offsets[node];
    int end = offsets[node + 1];

    for (int base = j; base < end; base += 64) {
        int idx = base + lane;
        int2 p = make_int2(0, 0);
        if (idx < end) p = payload[idx];
        int m = end - base;
        if (m > 64) m = 64;
        int psrc = p.x;
        int ppk  = p.y;

        #pragma unroll 4
        for (int it = 0; it < m; ++it) {
            int src = __shfl(psrc, it, 64);
            int pk  = __shfl(ppk,  it, 64);
            float nl = __half2float(__ushort_as_half((unsigned short)(pk & 0xffff)));
            float cf = __half2float(__ushort_as_half((unsigned short)(((unsigned int)pk) >> 16)));
            uint2 raw = *(const uint2*)(nfb + (long)src * RLC + f0);
            float fx = __uint_as_float(raw.x << 16);
            float fy = __uint_as_float(raw.x & 0xffff0000u);
            float fz = __uint_as_float(raw.y << 16);
            float fw = __uint_as_float(raw.y & 0xffff0000u);
            ax += fx * (fast_exp2(nl * iv.x) * pf.x * cf);
            ay += fy * (fast_exp2(nl * iv.y) * pf.y * cf);
            az += fz * (fast_exp2(nl * iv.z) * pf.z * cf);
            aw += fw * (fast_exp2(nl * iv.w) * pf.w * cf);
        }
    }

    *(float4*)(out + (long)node * RLC + f0) = make_float4(ax, ay, az, aw);
}

// ===========================================================================
// TIER 3: atomic scatter (no ws)
// ===========================================================================
__global__ __launch_bounds__(256) void init_out_kernel(
    const float4* __restrict__ nf4, float4* __restrict__ out4,
    const float* __restrict__ coef_p, int n4)
{
    int i = blockIdx.x * blockDim.x + threadIdx.x;
    if (i >= n4) return;
    float c = *coef_p;
    float4 v = nf4[i];
    out4[i] = make_float4(v.x * c, v.y * c, v.z * c, v.w * c);
}

__global__ __launch_bounds__(256) void edge_scatter_kernel(
    const float* __restrict__ node_feat,
    const float* __restrict__ edge_len,
    const float* __restrict__ cutoff_fn,
    const int*  __restrict__ edge_index,
    const float* __restrict__ prefactor,
    const float* __restrict__ invr0,
    float* __restrict__ out, int n_edges)
{
    int tid  = blockIdx.x * blockDim.x + threadIdx.x;
    int e    = tid >> 6;
    int lane = threadIdx.x & 63;
    if (e >= n_edges) return;
    int   src = edge_index[e];
    int   dst = edge_index[n_edges + e];
    float len = edge_len[e];
    float cf  = cutoff_fn[e];
    int f0     = lane << 2;
    int rcbase = ((f0 >> 5) << 3) + (f0 & 7);
    const float4 iv = *(const float4*)(invr0 + rcbase);
    const float4 pf = *(const float4*)(prefactor + rcbase);
    const float4 s  = *(const float4*)(node_feat + (long)src * RLC + f0);
    float nl = -len;
    float* o = out + (long)dst * RLC + f0;
    atomicAdd(o + 0, s.x * __expf(nl * iv.x) * pf.x * cf);
    atomicAdd(o + 1, s.y * __expf(nl * iv.y) * pf.y * cf);
    atomicAdd(o + 2, s.z * __expf(nl * iv.z) * pf.z * cf);
    atomicAdd(o + 3, s.w * __expf(nl * iv.w) * pf.w * cf);
}

extern "C" void kernel_launch(void* const* d_in, const int* in_sizes, int n_in,
                              void* d_out, int out_size, void* d_ws, size_t ws_size,
                              hipStream_t stream) {
    const float* node_feat  = (const float*)d_in[0];
    const float* edge_len   = (const float*)d_in[1];
    const float* cutoff_fn  = (const float*)d_in[2];
    const int*   edge_index = (const int*)d_in[3];
    const float* prefactor  = (const float*)d_in[4];
    const float* invr0      = (const float*)d_in[5];
    const float* coef_p     = (const float*)d_in[6];
    float* out = (float*)d_out;

    const int n_edges = in_sizes[1];
    const int n_feat  = in_sizes[0];
    const int n_nodes = n_feat / RLC;

    // TIER 1 layout: nfbT | payload | ovf | counts | ovf_cnt
    size_t need1 = (size_t)n_feat * 2
                 + (size_t)n_nodes * BUCKET * 8
                 + (size_t)OVF_CAP * 16
                 + (size_t)(n_nodes + 1) * 4;

    const int per_block = SCAN_BLOCK * SCAN_ITEMS;
    const int nb1 = (n_nodes + per_block - 1) / per_block;
    size_t need2 = (size_t)n_feat * 2
                 + (size_t)n_edges * 8
                 + ((size_t)(n_nodes + 1) + n_nodes + 256) * 4
                 + (size_t)n_edges;

    if (ws_size >= need1) {
        unsigned short* nfbT = (unsigned short*)d_ws;
        int2* payload = (int2*)(nfbT + n_feat);
        int4* ovf     = (int4*)(payload + (size_t)n_nodes * BUCKET);
        int*  counts  = (int*)(ovf + OVF_CAP);
        int*  ovf_cnt = counts + n_nodes;

        int nr = n_nodes * 8;
        cast_t_kernel<<<(nr + 255) / 256, 256, 0, stream>>>(
            (const float4*)node_feat, (uint2*)nfbT, nr);

        (void)hipMemsetAsync(counts, 0, (size_t)(n_nodes + 1) * sizeof(int), stream);

        int eg = (n_edges + 255) / 256;
        build_kernel<<<eg, 256, 0, stream>>>(
            edge_index, edge_len, cutoff_fn, counts, payload, ovf, ovf_cnt, n_edges);

        int gg = (n_nodes + 3) / 4;
        gather_bucket_kernel<<<gg, 256, 0, stream>>>(
            node_feat, nfbT, payload, prefactor, invr0, coef_p, counts,
            out, n_nodes);

        ovf_kernel<<<64, 256, 0, stream>>>(
            nfbT, prefactor, invr0, ovf, ovf_cnt, out);
    } else if (ws_size >= need2 && nb1 <= SCAN_BLOCK) {
        unsigned short* nfb = (unsigned short*)d_ws;
        int2* payload   = (int2*)(nfb + n_feat);
        int* offsets    = (int*)(payload + n_edges);
        int* counts     = offsets + (n_nodes + 1);
        int* blocksums  = counts + n_nodes;
        unsigned char* rank = (unsigned char*)(blocksums + 256);

        int n8 = n_feat / 8;
        cast_kernel<<<(n8 + 255) / 256, 256, 0, stream>>>(
            (const float4*)node_feat, (uint4*)nfb, n8);

        (void)hipMemsetAsync(counts, 0, (size_t)n_nodes * sizeof(int), stream);

        int eg = (n_edges + 255) / 256;
        hist_rank_kernel<<<eg, 256, 0, stream>>>(edge_index, counts, rank, n_edges);
        scan1_kernel<<<nb1, SCAN_BLOCK, 0, stream>>>(counts, offsets, blocksums, n_nodes);
        scan2_kernel<<<1, SCAN_BLOCK, 0, stream>>>(blocksums, nb1);
        int ng = (n_nodes + 255) / 256;
        scan3_kernel<<<ng, 256, 0, stream>>>(offsets, blocksums, n_nodes, n_edges);
        scatter_rank_kernel<<<eg, 256, 0, stream>>>(
            edge_index, edge_len, cutoff_fn, offsets, rank, payload, n_edges);

        long total = (long)n_nodes * 64;
        int gg = (int)((total + 255) / 256);
        gather_kernel<<<gg, 256, 0, stream>>>(
            node_feat, nfb, payload, prefactor, invr0, coef_p, offsets,
            out, n_nodes);
    } else {
        int n4 = n_feat / 4;
        init_out_kernel<<<(n4 + 255) / 256, 256, 0, stream>>>(
            (const float4*)node_feat, (float4*)out, coef_p, n4);
        long total_threads = (long)n_edges * 64;
        int grid = (int)((total_threads + 255) / 256);
        edge_scatter_kernel<<<grid, 256, 0, stream>>>(
            node_feat, edge_len, cutoff_fn, edge_index,
            prefactor, invr0, out, n_edges);
    }
}